// Round 1
// baseline (1135.431 us; speedup 1.0000x reference)
//
#include <hip/hip_runtime.h>

#define BDIM 256

// feature_maps: [B,V,C,H,W] f32  (B=2,V=4,C=32,H=512,W=640)
// pts:          [B,3,N]     f32
// cam_intrinsics: [B,V,3,3] f32
// cam_extrinsics: [B,V,3,4] f32
// out:          [B,V,C,N]   f32
__global__ __launch_bounds__(BDIM) void feature_fetch_kernel(
    const float* __restrict__ fm,
    const float* __restrict__ pts,
    const float* __restrict__ Kmat,
    const float* __restrict__ Emat,
    float* __restrict__ out,
    int N)
{
    constexpr int C = 32, H = 512, W = 640;
    const int bv = blockIdx.y;       // 0..7
    const int b  = bv >> 2;          // V = 4
    const int n  = blockIdx.x * BDIM + threadIdx.x;
    if (n >= N) return;

    // Wave-uniform camera params (blockIdx.y-indexed -> scalar loads)
    const float* Kp = Kmat + bv * 9;
    const float* Ep = Emat + bv * 12;

    const float px = pts[(size_t)(b * 3 + 0) * N + n];
    const float py = pts[(size_t)(b * 3 + 1) * N + n];
    const float pz = pts[(size_t)(b * 3 + 2) * N + n];

    // tp = E[:, :3] @ p + t
    const float X = fmaf(Ep[0], px, fmaf(Ep[1], py, fmaf(Ep[2], pz, Ep[3])));
    const float Y = fmaf(Ep[4], px, fmaf(Ep[5], py, fmaf(Ep[6], pz, Ep[7])));
    const float Z = fmaf(Ep[8], px, fmaf(Ep[9], py, fmaf(Ep[10], pz, Ep[11])));

    const bool zzero = (Z == 0.0f);
    const float zs = zzero ? 1.0f : Z;
    const float xn = X / zs;
    const float yn = Y / zs;
    float u = fmaf(Kp[0], xn, fmaf(Kp[1], yn, Kp[2]));
    float v = fmaf(Kp[3], xn, fmaf(Kp[4], yn, Kp[5]));
    if (zzero) { u = 2.0f * W; v = 2.0f * H; }

    // ix = (gx+1)*0.5*(W-1) with gx=(u-0.5)/(W-1)*2-1 simplifies to u-0.5
    const float ix = u - 0.5f;
    const float iy = v - 0.5f;
    const float x0f = floorf(ix);
    const float y0f = floorf(iy);
    const float wx1 = ix - x0f, wx0 = 1.0f - wx1;
    const float wy1 = iy - y0f, wy0 = 1.0f - wy1;

    // corner validity (zeros padding), indices clamped for the load
    const bool vx0 = (x0f >= 0.0f)  && (x0f <= (float)(W - 1));
    const bool vx1 = (x0f >= -1.0f) && (x0f <= (float)(W - 2));
    const bool vy0 = (y0f >= 0.0f)  && (y0f <= (float)(H - 1));
    const bool vy1 = (y0f >= -1.0f) && (y0f <= (float)(H - 2));

    const int x0c = (int)fminf(fmaxf(x0f,        0.0f), (float)(W - 1));
    const int x1c = (int)fminf(fmaxf(x0f + 1.0f, 0.0f), (float)(W - 1));
    const int y0c = (int)fminf(fmaxf(y0f,        0.0f), (float)(H - 1));
    const int y1c = (int)fminf(fmaxf(y0f + 1.0f, 0.0f), (float)(H - 1));

    const float w00 = wx0 * wy0 * ((vx0 && vy0) ? 1.0f : 0.0f);
    const float w10 = wx1 * wy0 * ((vx1 && vy0) ? 1.0f : 0.0f);
    const float w01 = wx0 * wy1 * ((vx0 && vy1) ? 1.0f : 0.0f);
    const float w11 = wx1 * wy1 * ((vx1 && vy1) ? 1.0f : 0.0f);

    const int i00 = y0c * W + x0c;
    const int i10 = y0c * W + x1c;
    const int i01 = y1c * W + x0c;
    const int i11 = y1c * W + x1c;

    const float* base  = fm  + (size_t)bv * C * H * W;
    float*       obase = out + (size_t)bv * C * N + n;

    #pragma unroll 4
    for (int c = 0; c < C; ++c) {
        const float* p = base + (size_t)c * (H * W);
        const float val = p[i00] * w00 + p[i10] * w10
                        + p[i01] * w01 + p[i11] * w11;
        obase[(size_t)c * N] = val;
    }
}

extern "C" void kernel_launch(void* const* d_in, const int* in_sizes, int n_in,
                              void* d_out, int out_size, void* d_ws, size_t ws_size,
                              hipStream_t stream) {
    const float* fm  = (const float*)d_in[0];
    const float* pts = (const float*)d_in[1];
    const float* K   = (const float*)d_in[2];
    const float* E   = (const float*)d_in[3];
    float* out = (float*)d_out;

    const int N = in_sizes[1] / 6;   // pts is [B=2, 3, N]
    dim3 grid((N + BDIM - 1) / BDIM, 8 /* B*V */);
    feature_fetch_kernel<<<grid, BDIM, 0, stream>>>(fm, pts, K, E, out, N);
}

// Round 2
// 236.281 us; speedup vs baseline: 4.8054x; 4.8054x over previous
//
#include <hip/hip_runtime.h>

#define BDIM 256

constexpr int Cc = 32, Hh = 512, Ww = 640, HW = Hh * Ww, NBV = 8;

__device__ __forceinline__ unsigned short f32_to_bf16_rne(float f) {
    unsigned int u = __float_as_uint(f);
    u = (u + 0x7fffu + ((u >> 16) & 1u)) >> 16;
    return (unsigned short)u;
}

// fm [BV][C][HW] f32  ->  ws [BV][HW][C] bf16
__global__ __launch_bounds__(256) void transpose_kernel(
    const float* __restrict__ fm, unsigned short* __restrict__ ws)
{
    __shared__ float lds[32 * 260];
    const int bv  = blockIdx.y;
    const int p0  = blockIdx.x * 256;          // pixel tile base (HW % 256 == 0)
    const int tid = threadIdx.x;
    const int m   = tid & 63;                  // lane within quarter-group
    const int g   = tid >> 6;                  // 0..3

    const float4* src = (const float4*)(fm + (size_t)bv * Cc * HW);
    #pragma unroll
    for (int it = 0; it < 8; ++it) {
        const int c = it * 4 + g;
        float4 v = src[(size_t)((c * HW + p0) >> 2) + m];
        *(float4*)&lds[c * 260 + 4 * m] = v;   // byte addr: c*1040 + 16m, 16B-aligned
    }
    __syncthreads();

    const int q     = tid & 7;                 // channel quad 0..7
    const int pbase = tid >> 3;                // 0..31
    unsigned short* dst = ws + ((size_t)bv * HW + p0) * Cc;
    #pragma unroll
    for (int it = 0; it < 8; ++it) {
        const int pp = it * 32 + pbase;
        ushort4 o;
        o.x = f32_to_bf16_rne(lds[(4 * q + 0) * 260 + pp]);
        o.y = f32_to_bf16_rne(lds[(4 * q + 1) * 260 + pp]);
        o.z = f32_to_bf16_rne(lds[(4 * q + 2) * 260 + pp]);
        o.w = f32_to_bf16_rne(lds[(4 * q + 3) * 260 + pp]);
        *(ushort4*)&dst[(size_t)pp * Cc + 4 * q] = o;  // 8B-aligned, coalesced
    }
}

__device__ __forceinline__ void acc_corner(const unsigned short* cp, float wgt,
                                           float* acc)
{
    const uint4* p = (const uint4*)cp;         // 64B-aligned (idx*32 bf16)
    #pragma unroll
    for (int i = 0; i < 4; ++i) {
        uint4 v = p[i];
        unsigned int a[4] = {v.x, v.y, v.z, v.w};
        #pragma unroll
        for (int j = 0; j < 4; ++j) {
            unsigned int u = a[j];
            float lo = __uint_as_float(u << 16);
            float hi = __uint_as_float(u & 0xffff0000u);
            acc[i * 8 + 2 * j + 0] = fmaf(lo, wgt, acc[i * 8 + 2 * j + 0]);
            acc[i * 8 + 2 * j + 1] = fmaf(hi, wgt, acc[i * 8 + 2 * j + 1]);
        }
    }
}

__global__ __launch_bounds__(BDIM) void gather_kernel(
    const unsigned short* __restrict__ ws,
    const float* __restrict__ pts,
    const float* __restrict__ Kmat,
    const float* __restrict__ Emat,
    float* __restrict__ out,
    int N)
{
    const int bv = blockIdx.y;
    const int b  = bv >> 2;
    const int n  = blockIdx.x * BDIM + threadIdx.x;
    if (n >= N) return;

    const float* Kp = Kmat + bv * 9;
    const float* Ep = Emat + bv * 12;

    const float px = pts[(size_t)(b * 3 + 0) * N + n];
    const float py = pts[(size_t)(b * 3 + 1) * N + n];
    const float pz = pts[(size_t)(b * 3 + 2) * N + n];

    const float X = fmaf(Ep[0], px, fmaf(Ep[1], py, fmaf(Ep[2], pz, Ep[3])));
    const float Y = fmaf(Ep[4], px, fmaf(Ep[5], py, fmaf(Ep[6], pz, Ep[7])));
    const float Z = fmaf(Ep[8], px, fmaf(Ep[9], py, fmaf(Ep[10], pz, Ep[11])));

    const bool zzero = (Z == 0.0f);
    const float zs = zzero ? 1.0f : Z;
    const float xn = X / zs;
    const float yn = Y / zs;
    float u = fmaf(Kp[0], xn, fmaf(Kp[1], yn, Kp[2]));
    float v = fmaf(Kp[3], xn, fmaf(Kp[4], yn, Kp[5]));
    if (zzero) { u = 2.0f * Ww; v = 2.0f * Hh; }

    const float ix = u - 0.5f;
    const float iy = v - 0.5f;
    const float x0f = floorf(ix);
    const float y0f = floorf(iy);
    const float wx1 = ix - x0f, wx0 = 1.0f - wx1;
    const float wy1 = iy - y0f, wy0 = 1.0f - wy1;

    const bool vx0 = (x0f >= 0.0f)  && (x0f <= (float)(Ww - 1));
    const bool vx1 = (x0f >= -1.0f) && (x0f <= (float)(Ww - 2));
    const bool vy0 = (y0f >= 0.0f)  && (y0f <= (float)(Hh - 1));
    const bool vy1 = (y0f >= -1.0f) && (y0f <= (float)(Hh - 2));

    const int x0c = (int)fminf(fmaxf(x0f,        0.0f), (float)(Ww - 1));
    const int x1c = (int)fminf(fmaxf(x0f + 1.0f, 0.0f), (float)(Ww - 1));
    const int y0c = (int)fminf(fmaxf(y0f,        0.0f), (float)(Hh - 1));
    const int y1c = (int)fminf(fmaxf(y0f + 1.0f, 0.0f), (float)(Hh - 1));

    const float w00 = wx0 * wy0 * ((vx0 && vy0) ? 1.0f : 0.0f);
    const float w10 = wx1 * wy0 * ((vx1 && vy0) ? 1.0f : 0.0f);
    const float w01 = wx0 * wy1 * ((vx0 && vy1) ? 1.0f : 0.0f);
    const float w11 = wx1 * wy1 * ((vx1 && vy1) ? 1.0f : 0.0f);

    const unsigned short* base = ws + (size_t)bv * HW * Cc;
    float acc[32];
    #pragma unroll
    for (int c = 0; c < 32; ++c) acc[c] = 0.0f;

    acc_corner(base + (size_t)(y0c * Ww + x0c) * Cc, w00, acc);
    acc_corner(base + (size_t)(y0c * Ww + x1c) * Cc, w10, acc);
    acc_corner(base + (size_t)(y1c * Ww + x0c) * Cc, w01, acc);
    acc_corner(base + (size_t)(y1c * Ww + x1c) * Cc, w11, acc);

    float* obase = out + (size_t)bv * Cc * N + n;
    #pragma unroll
    for (int c = 0; c < 32; ++c) obase[(size_t)c * N] = acc[c];
}

// ---------------- fallback (R1 kernel) if ws too small ----------------
__global__ __launch_bounds__(BDIM) void feature_fetch_fallback(
    const float* __restrict__ fm, const float* __restrict__ pts,
    const float* __restrict__ Kmat, const float* __restrict__ Emat,
    float* __restrict__ out, int N)
{
    const int bv = blockIdx.y;
    const int b  = bv >> 2;
    const int n  = blockIdx.x * BDIM + threadIdx.x;
    if (n >= N) return;
    const float* Kp = Kmat + bv * 9;
    const float* Ep = Emat + bv * 12;
    const float px = pts[(size_t)(b * 3 + 0) * N + n];
    const float py = pts[(size_t)(b * 3 + 1) * N + n];
    const float pz = pts[(size_t)(b * 3 + 2) * N + n];
    const float X = fmaf(Ep[0], px, fmaf(Ep[1], py, fmaf(Ep[2], pz, Ep[3])));
    const float Y = fmaf(Ep[4], px, fmaf(Ep[5], py, fmaf(Ep[6], pz, Ep[7])));
    const float Z = fmaf(Ep[8], px, fmaf(Ep[9], py, fmaf(Ep[10], pz, Ep[11])));
    const bool zzero = (Z == 0.0f);
    const float zs = zzero ? 1.0f : Z;
    const float xn = X / zs, yn = Y / zs;
    float u = fmaf(Kp[0], xn, fmaf(Kp[1], yn, Kp[2]));
    float v = fmaf(Kp[3], xn, fmaf(Kp[4], yn, Kp[5]));
    if (zzero) { u = 2.0f * Ww; v = 2.0f * Hh; }
    const float ix = u - 0.5f, iy = v - 0.5f;
    const float x0f = floorf(ix), y0f = floorf(iy);
    const float wx1 = ix - x0f, wx0 = 1.0f - wx1;
    const float wy1 = iy - y0f, wy0 = 1.0f - wy1;
    const bool vx0 = (x0f >= 0.0f) && (x0f <= (float)(Ww - 1));
    const bool vx1 = (x0f >= -1.0f) && (x0f <= (float)(Ww - 2));
    const bool vy0 = (y0f >= 0.0f) && (y0f <= (float)(Hh - 1));
    const bool vy1 = (y0f >= -1.0f) && (y0f <= (float)(Hh - 2));
    const int x0c = (int)fminf(fmaxf(x0f, 0.0f), (float)(Ww - 1));
    const int x1c = (int)fminf(fmaxf(x0f + 1.0f, 0.0f), (float)(Ww - 1));
    const int y0c = (int)fminf(fmaxf(y0f, 0.0f), (float)(Hh - 1));
    const int y1c = (int)fminf(fmaxf(y0f + 1.0f, 0.0f), (float)(Hh - 1));
    const float w00 = wx0 * wy0 * ((vx0 && vy0) ? 1.0f : 0.0f);
    const float w10 = wx1 * wy0 * ((vx1 && vy0) ? 1.0f : 0.0f);
    const float w01 = wx0 * wy1 * ((vx0 && vy1) ? 1.0f : 0.0f);
    const float w11 = wx1 * wy1 * ((vx1 && vy1) ? 1.0f : 0.0f);
    const int i00 = y0c * Ww + x0c, i10 = y0c * Ww + x1c;
    const int i01 = y1c * Ww + x0c, i11 = y1c * Ww + x1c;
    const float* basep = fm + (size_t)bv * Cc * HW;
    float* obase = out + (size_t)bv * Cc * N + n;
    #pragma unroll 4
    for (int c = 0; c < Cc; ++c) {
        const float* p = basep + (size_t)c * HW;
        obase[(size_t)c * N] = p[i00] * w00 + p[i10] * w10 + p[i01] * w01 + p[i11] * w11;
    }
}

extern "C" void kernel_launch(void* const* d_in, const int* in_sizes, int n_in,
                              void* d_out, int out_size, void* d_ws, size_t ws_size,
                              hipStream_t stream) {
    const float* fm  = (const float*)d_in[0];
    const float* pts = (const float*)d_in[1];
    const float* K   = (const float*)d_in[2];
    const float* E   = (const float*)d_in[3];
    float* out = (float*)d_out;
    const int N = in_sizes[1] / 6;   // pts is [B=2, 3, N]

    const size_t need = (size_t)NBV * HW * Cc * sizeof(unsigned short); // 160 MB
    if (ws_size >= need) {
        unsigned short* ws = (unsigned short*)d_ws;
        dim3 tgrid(HW / 256, NBV);
        transpose_kernel<<<tgrid, 256, 0, stream>>>(fm, ws);
        dim3 ggrid((N + BDIM - 1) / BDIM, NBV);
        gather_kernel<<<ggrid, BDIM, 0, stream>>>(ws, pts, K, E, out, N);
    } else {
        dim3 grid((N + BDIM - 1) / BDIM, NBV);
        feature_fetch_fallback<<<grid, BDIM, 0, stream>>>(fm, pts, K, E, out, N);
    }
}

// Round 4
// 186.194 us; speedup vs baseline: 6.0981x; 1.2690x over previous
//
#include <hip/hip_runtime.h>

#define BDIM 256

constexpr int Cc = 32, Hh = 512, Ww = 640, HW = Hh * Ww, NBV = 8;

typedef float  fx4 __attribute__((ext_vector_type(4)));
typedef unsigned int ux4 __attribute__((ext_vector_type(4)));

__device__ __forceinline__ unsigned short f32_to_bf16_rne(float f) {
    unsigned int u = __float_as_uint(f);
    u = (u + 0x7fffu + ((u >> 16) & 1u)) >> 16;
    return (unsigned short)u;
}

// fm [BV][C][HW] f32  ->  ws [BV][HW][C] bf16
__global__ __launch_bounds__(256) void transpose_kernel(
    const float* __restrict__ fm, unsigned short* __restrict__ ws)
{
    __shared__ float lds[32 * 260];
    const int bv  = blockIdx.y;
    const int p0  = blockIdx.x * 256;          // pixel tile base (HW % 256 == 0)
    const int tid = threadIdx.x;
    const int m   = tid & 63;
    const int g   = tid >> 6;                  // 0..3

    const fx4* src = (const fx4*)(fm + (size_t)bv * Cc * HW);
    #pragma unroll
    for (int it = 0; it < 8; ++it) {
        const int c = it * 4 + g;
        // non-temporal: fm is streamed exactly once; don't evict ws from L3
        fx4 v = __builtin_nontemporal_load(&src[(size_t)((c * HW + p0) >> 2) + m]);
        *(fx4*)&lds[c * 260 + 4 * m] = v;
    }
    __syncthreads();

    const int q     = tid & 7;                 // channel quad 0..7
    const int pbase = tid >> 3;                // 0..31
    unsigned short* dst = ws + ((size_t)bv * HW + p0) * Cc;
    #pragma unroll
    for (int it = 0; it < 8; ++it) {
        const int pp = it * 32 + pbase;
        ushort4 o;
        o.x = f32_to_bf16_rne(lds[(4 * q + 0) * 260 + pp]);
        o.y = f32_to_bf16_rne(lds[(4 * q + 1) * 260 + pp]);
        o.z = f32_to_bf16_rne(lds[(4 * q + 2) * 260 + pp]);
        o.w = f32_to_bf16_rne(lds[(4 * q + 3) * 260 + pp]);
        *(ushort4*)&dst[(size_t)pp * Cc + 4 * q] = o;
    }
}

// Quad-cooperative gather: 4 lanes per point, each lane owns 8 channels (16B
// of each 64B pixel record) -> the quad's corner loads coalesce into ONE
// cache-line request instead of 4 distinct-line requests.
__global__ __launch_bounds__(BDIM) void gather_kernel(
    const unsigned short* __restrict__ ws,
    const float* __restrict__ pts,
    const float* __restrict__ Kmat,
    const float* __restrict__ Emat,
    float* __restrict__ out,
    int N)
{
    const int bv  = blockIdx.y;
    const int b   = bv >> 2;
    const int tid = threadIdx.x;
    const int q   = tid & 3;                   // channel chunk 0..3 (8 ch each)
    const int n   = blockIdx.x * (BDIM / 4) + (tid >> 2);
    if (n >= N) return;

    const float* Kp = Kmat + bv * 9;
    const float* Ep = Emat + bv * 12;

    const float px = pts[(size_t)(b * 3 + 0) * N + n];
    const float py = pts[(size_t)(b * 3 + 1) * N + n];
    const float pz = pts[(size_t)(b * 3 + 2) * N + n];

    const float X = fmaf(Ep[0], px, fmaf(Ep[1], py, fmaf(Ep[2], pz, Ep[3])));
    const float Y = fmaf(Ep[4], px, fmaf(Ep[5], py, fmaf(Ep[6], pz, Ep[7])));
    const float Z = fmaf(Ep[8], px, fmaf(Ep[9], py, fmaf(Ep[10], pz, Ep[11])));

    const bool zzero = (Z == 0.0f);
    const float zs = zzero ? 1.0f : Z;
    const float xn = X / zs;
    const float yn = Y / zs;
    float u = fmaf(Kp[0], xn, fmaf(Kp[1], yn, Kp[2]));
    float v = fmaf(Kp[3], xn, fmaf(Kp[4], yn, Kp[5]));
    if (zzero) { u = 2.0f * Ww; v = 2.0f * Hh; }

    const float ix = u - 0.5f;
    const float iy = v - 0.5f;
    const float x0f = floorf(ix);
    const float y0f = floorf(iy);
    const float wx1 = ix - x0f, wx0 = 1.0f - wx1;
    const float wy1 = iy - y0f, wy0 = 1.0f - wy1;

    const bool vx0 = (x0f >= 0.0f)  && (x0f <= (float)(Ww - 1));
    const bool vx1 = (x0f >= -1.0f) && (x0f <= (float)(Ww - 2));
    const bool vy0 = (y0f >= 0.0f)  && (y0f <= (float)(Hh - 1));
    const bool vy1 = (y0f >= -1.0f) && (y0f <= (float)(Hh - 2));

    const int x0c = (int)fminf(fmaxf(x0f,        0.0f), (float)(Ww - 1));
    const int x1c = (int)fminf(fmaxf(x0f + 1.0f, 0.0f), (float)(Ww - 1));
    const int y0c = (int)fminf(fmaxf(y0f,        0.0f), (float)(Hh - 1));
    const int y1c = (int)fminf(fmaxf(y0f + 1.0f, 0.0f), (float)(Hh - 1));

    const float w00 = wx0 * wy0 * ((vx0 && vy0) ? 1.0f : 0.0f);
    const float w10 = wx1 * wy0 * ((vx1 && vy0) ? 1.0f : 0.0f);
    const float w01 = wx0 * wy1 * ((vx0 && vy1) ? 1.0f : 0.0f);
    const float w11 = wx1 * wy1 * ((vx1 && vy1) ? 1.0f : 0.0f);

    const unsigned short* base = ws + (size_t)bv * HW * Cc + q * 8;
    const int idx[4] = { y0c * Ww + x0c, y0c * Ww + x1c,
                         y1c * Ww + x0c, y1c * Ww + x1c };
    const float wgt[4] = { w00, w10, w01, w11 };

    float acc[8];
    #pragma unroll
    for (int j = 0; j < 8; ++j) acc[j] = 0.0f;

    #pragma unroll
    for (int k = 0; k < 4; ++k) {
        const ux4 vv = *(const ux4*)(base + (size_t)idx[k] * Cc);
        const float w = wgt[k];
        #pragma unroll
        for (int j = 0; j < 4; ++j) {
            const unsigned int uu = vv[j];
            acc[2 * j + 0] = fmaf(__uint_as_float(uu << 16),         w, acc[2 * j + 0]);
            acc[2 * j + 1] = fmaf(__uint_as_float(uu & 0xffff0000u), w, acc[2 * j + 1]);
        }
    }

    // out[bv][c][n], c = 8q..8q+7; non-temporal (never re-read; keep ws in L3)
    float* obase = out + (size_t)bv * Cc * N + (size_t)(8 * q) * N + n;
    #pragma unroll
    for (int j = 0; j < 8; ++j)
        __builtin_nontemporal_store(acc[j], &obase[(size_t)j * N]);
}

// ---------------- fallback (R1 kernel) if ws too small ----------------
__global__ __launch_bounds__(BDIM) void feature_fetch_fallback(
    const float* __restrict__ fm, const float* __restrict__ pts,
    const float* __restrict__ Kmat, const float* __restrict__ Emat,
    float* __restrict__ out, int N)
{
    const int bv = blockIdx.y;
    const int b  = bv >> 2;
    const int n  = blockIdx.x * BDIM + threadIdx.x;
    if (n >= N) return;
    const float* Kp = Kmat + bv * 9;
    const float* Ep = Emat + bv * 12;
    const float px = pts[(size_t)(b * 3 + 0) * N + n];
    const float py = pts[(size_t)(b * 3 + 1) * N + n];
    const float pz = pts[(size_t)(b * 3 + 2) * N + n];
    const float X = fmaf(Ep[0], px, fmaf(Ep[1], py, fmaf(Ep[2], pz, Ep[3])));
    const float Y = fmaf(Ep[4], px, fmaf(Ep[5], py, fmaf(Ep[6], pz, Ep[7])));
    const float Z = fmaf(Ep[8], px, fmaf(Ep[9], py, fmaf(Ep[10], pz, Ep[11])));
    const bool zzero = (Z == 0.0f);
    const float zs = zzero ? 1.0f : Z;
    const float xn = X / zs, yn = Y / zs;
    float u = fmaf(Kp[0], xn, fmaf(Kp[1], yn, Kp[2]));
    float v = fmaf(Kp[3], xn, fmaf(Kp[4], yn, Kp[5]));
    if (zzero) { u = 2.0f * Ww; v = 2.0f * Hh; }
    const float ix = u - 0.5f, iy = v - 0.5f;
    const float x0f = floorf(ix), y0f = floorf(iy);
    const float wx1 = ix - x0f, wx0 = 1.0f - wx1;
    const float wy1 = iy - y0f, wy0 = 1.0f - wy1;
    const bool vx0 = (x0f >= 0.0f) && (x0f <= (float)(Ww - 1));
    const bool vx1 = (x0f >= -1.0f) && (x0f <= (float)(Ww - 2));
    const bool vy0 = (y0f >= 0.0f) && (y0f <= (float)(Hh - 1));
    const bool vy1 = (y0f >= -1.0f) && (y0f <= (float)(Hh - 2));
    const int x0c = (int)fminf(fmaxf(x0f, 0.0f), (float)(Ww - 1));
    const int x1c = (int)fminf(fmaxf(x0f + 1.0f, 0.0f), (float)(Ww - 1));
    const int y0c = (int)fminf(fmaxf(y0f, 0.0f), (float)(Hh - 1));
    const int y1c = (int)fminf(fmaxf(y0f + 1.0f, 0.0f), (float)(Hh - 1));
    const float w00 = wx0 * wy0 * ((vx0 && vy0) ? 1.0f : 0.0f);
    const float w10 = wx1 * wy0 * ((vx1 && vy0) ? 1.0f : 0.0f);
    const float w01 = wx0 * wy1 * ((vx0 && vy1) ? 1.0f : 0.0f);
    const float w11 = wx1 * wy1 * ((vx1 && vy1) ? 1.0f : 0.0f);
    const int i00 = y0c * Ww + x0c, i10 = y0c * Ww + x1c;
    const int i01 = y1c * Ww + x0c, i11 = y1c * Ww + x1c;
    const float* basep = fm + (size_t)bv * Cc * HW;
    float* obase = out + (size_t)bv * Cc * N + n;
    #pragma unroll 4
    for (int c = 0; c < Cc; ++c) {
        const float* p = basep + (size_t)c * HW;
        obase[(size_t)c * N] = p[i00] * w00 + p[i10] * w10 + p[i01] * w01 + p[i11] * w11;
    }
}

extern "C" void kernel_launch(void* const* d_in, const int* in_sizes, int n_in,
                              void* d_out, int out_size, void* d_ws, size_t ws_size,
                              hipStream_t stream) {
    const float* fm  = (const float*)d_in[0];
    const float* pts = (const float*)d_in[1];
    const float* K   = (const float*)d_in[2];
    const float* E   = (const float*)d_in[3];
    float* out = (float*)d_out;
    const int N = in_sizes[1] / 6;   // pts is [B=2, 3, N]

    const size_t need = (size_t)NBV * HW * Cc * sizeof(unsigned short); // 160 MB
    if (ws_size >= need) {
        unsigned short* ws = (unsigned short*)d_ws;
        dim3 tgrid(HW / 256, NBV);
        transpose_kernel<<<tgrid, 256, 0, stream>>>(fm, ws);
        const int pts_per_block = BDIM / 4;   // 64 points/block
        dim3 ggrid((N + pts_per_block - 1) / pts_per_block, NBV);
        gather_kernel<<<ggrid, BDIM, 0, stream>>>(ws, pts, K, E, out, N);
    } else {
        dim3 grid((N + BDIM - 1) / BDIM, NBV);
        feature_fetch_fallback<<<grid, BDIM, 0, stream>>>(fm, pts, K, E, out, N);
    }
}

// Round 5
// 180.306 us; speedup vs baseline: 6.2972x; 1.0327x over previous
//
#include <hip/hip_runtime.h>

#define BDIM 256

constexpr int Cc = 32, Hh = 512, Ww = 640, HW = Hh * Ww, NBV = 8;

typedef float  fx4 __attribute__((ext_vector_type(4)));
typedef float  fx2 __attribute__((ext_vector_type(2)));
typedef unsigned int ux4 __attribute__((ext_vector_type(4)));

__device__ __forceinline__ unsigned short f32_to_bf16_rne(float f) {
    unsigned int u = __float_as_uint(f);
    u = (u + 0x7fffu + ((u >> 16) & 1u)) >> 16;
    return (unsigned short)u;
}

// fm [BV][C][HW] f32  ->  ws [BV][HW][C] bf16
__global__ __launch_bounds__(256) void transpose_kernel(
    const float* __restrict__ fm, unsigned short* __restrict__ ws)
{
    __shared__ float lds[32 * 260];
    const int bv  = blockIdx.y;
    const int p0  = blockIdx.x * 256;          // pixel tile base (HW % 256 == 0)
    const int tid = threadIdx.x;
    const int m   = tid & 63;
    const int g   = tid >> 6;                  // 0..3

    const fx4* src = (const fx4*)(fm + (size_t)bv * Cc * HW);
    #pragma unroll
    for (int it = 0; it < 8; ++it) {
        const int c = it * 4 + g;
        // non-temporal: fm is streamed exactly once; don't evict ws from L3
        fx4 v = __builtin_nontemporal_load(&src[(size_t)((c * HW + p0) >> 2) + m]);
        *(fx4*)&lds[c * 260 + 4 * m] = v;
    }
    __syncthreads();

    const int q     = tid & 7;                 // channel quad 0..7
    const int pbase = tid >> 3;                // 0..31
    unsigned short* dst = ws + ((size_t)bv * HW + p0) * Cc;
    #pragma unroll
    for (int it = 0; it < 8; ++it) {
        const int pp = it * 32 + pbase;
        ushort4 o;
        o.x = f32_to_bf16_rne(lds[(4 * q + 0) * 260 + pp]);
        o.y = f32_to_bf16_rne(lds[(4 * q + 1) * 260 + pp]);
        o.z = f32_to_bf16_rne(lds[(4 * q + 2) * 260 + pp]);
        o.w = f32_to_bf16_rne(lds[(4 * q + 3) * 260 + pp]);
        *(ushort4*)&dst[(size_t)pp * Cc + 4 * q] = o;
    }
}

// one point's projection -> 4 corner indices + weights
__device__ __forceinline__ void project_point(
    const float* Kp, const float* Ep,
    float px, float py, float pz, int* idx, float* wgt)
{
    const float X = fmaf(Ep[0], px, fmaf(Ep[1], py, fmaf(Ep[2], pz, Ep[3])));
    const float Y = fmaf(Ep[4], px, fmaf(Ep[5], py, fmaf(Ep[6], pz, Ep[7])));
    const float Z = fmaf(Ep[8], px, fmaf(Ep[9], py, fmaf(Ep[10], pz, Ep[11])));
    const bool zzero = (Z == 0.0f);
    const float zs = zzero ? 1.0f : Z;
    const float xn = X / zs;
    const float yn = Y / zs;
    float u = fmaf(Kp[0], xn, fmaf(Kp[1], yn, Kp[2]));
    float v = fmaf(Kp[3], xn, fmaf(Kp[4], yn, Kp[5]));
    if (zzero) { u = 2.0f * Ww; v = 2.0f * Hh; }
    const float ix = u - 0.5f;
    const float iy = v - 0.5f;
    const float x0f = floorf(ix);
    const float y0f = floorf(iy);
    const float wx1 = ix - x0f, wx0 = 1.0f - wx1;
    const float wy1 = iy - y0f, wy0 = 1.0f - wy1;
    const bool vx0 = (x0f >= 0.0f)  && (x0f <= (float)(Ww - 1));
    const bool vx1 = (x0f >= -1.0f) && (x0f <= (float)(Ww - 2));
    const bool vy0 = (y0f >= 0.0f)  && (y0f <= (float)(Hh - 1));
    const bool vy1 = (y0f >= -1.0f) && (y0f <= (float)(Hh - 2));
    const int x0c = (int)fminf(fmaxf(x0f,        0.0f), (float)(Ww - 1));
    const int x1c = (int)fminf(fmaxf(x0f + 1.0f, 0.0f), (float)(Ww - 1));
    const int y0c = (int)fminf(fmaxf(y0f,        0.0f), (float)(Hh - 1));
    const int y1c = (int)fminf(fmaxf(y0f + 1.0f, 0.0f), (float)(Hh - 1));
    wgt[0] = wx0 * wy0 * ((vx0 && vy0) ? 1.0f : 0.0f);
    wgt[1] = wx1 * wy0 * ((vx1 && vy0) ? 1.0f : 0.0f);
    wgt[2] = wx0 * wy1 * ((vx0 && vy1) ? 1.0f : 0.0f);
    wgt[3] = wx1 * wy1 * ((vx1 && vy1) ? 1.0f : 0.0f);
    idx[0] = y0c * Ww + x0c;
    idx[1] = y0c * Ww + x1c;
    idx[2] = y1c * Ww + x0c;
    idx[3] = y1c * Ww + x1c;
}

// Quad-cooperative, 2 points per thread: 8 independent corner loads in
// flight (2x the ILP of the 1-pt version) to hide L3/HBM gather latency.
__global__ __launch_bounds__(BDIM) void gather2_kernel(
    const unsigned short* __restrict__ ws,
    const float* __restrict__ pts,
    const float* __restrict__ Kmat,
    const float* __restrict__ Emat,
    float* __restrict__ out,
    int N)   // requires N even (launcher guarantees)
{
    const int bv  = blockIdx.y;
    const int b   = bv >> 2;
    const int tid = threadIdx.x;
    const int q   = tid & 3;                   // channel chunk 0..3 (8 ch each)
    const int n0  = (blockIdx.x * (BDIM / 4) + (tid >> 2)) * 2;
    if (n0 >= N) return;

    const float* Kp = Kmat + bv * 9;
    const float* Ep = Emat + bv * 12;

    const fx2 pxv = *(const fx2*)&pts[(size_t)(b * 3 + 0) * N + n0];
    const fx2 pyv = *(const fx2*)&pts[(size_t)(b * 3 + 1) * N + n0];
    const fx2 pzv = *(const fx2*)&pts[(size_t)(b * 3 + 2) * N + n0];

    int   idx[2][4];
    float wgt[2][4];
    project_point(Kp, Ep, pxv[0], pyv[0], pzv[0], idx[0], wgt[0]);
    project_point(Kp, Ep, pxv[1], pyv[1], pzv[1], idx[1], wgt[1]);

    const unsigned short* base = ws + (size_t)bv * HW * Cc + q * 8;

    float acc[2][8];
    #pragma unroll
    for (int t = 0; t < 2; ++t)
        #pragma unroll
        for (int j = 0; j < 8; ++j) acc[t][j] = 0.0f;

    #pragma unroll
    for (int t = 0; t < 2; ++t) {
        #pragma unroll
        for (int k = 0; k < 4; ++k) {
            const ux4 vv = *(const ux4*)(base + (size_t)idx[t][k] * Cc);
            const float w = wgt[t][k];
            #pragma unroll
            for (int j = 0; j < 4; ++j) {
                const unsigned int uu = vv[j];
                acc[t][2*j+0] = fmaf(__uint_as_float(uu << 16),         w, acc[t][2*j+0]);
                acc[t][2*j+1] = fmaf(__uint_as_float(uu & 0xffff0000u), w, acc[t][2*j+1]);
            }
        }
    }

    // out[bv][8q+j][n0..n0+1]; non-temporal (never re-read; keep ws in L3)
    float* obase = out + (size_t)bv * Cc * N + (size_t)(8 * q) * N + n0;
    #pragma unroll
    for (int j = 0; j < 8; ++j) {
        fx2 o = { acc[0][j], acc[1][j] };
        __builtin_nontemporal_store(o, (fx2*)&obase[(size_t)j * N]);
    }
}

// 1-pt/thread variant (used when N is odd)
__global__ __launch_bounds__(BDIM) void gather_kernel(
    const unsigned short* __restrict__ ws,
    const float* __restrict__ pts,
    const float* __restrict__ Kmat,
    const float* __restrict__ Emat,
    float* __restrict__ out,
    int N)
{
    const int bv  = blockIdx.y;
    const int b   = bv >> 2;
    const int tid = threadIdx.x;
    const int q   = tid & 3;
    const int n   = blockIdx.x * (BDIM / 4) + (tid >> 2);
    if (n >= N) return;

    const float* Kp = Kmat + bv * 9;
    const float* Ep = Emat + bv * 12;

    int   idx[4];
    float wgt[4];
    project_point(Kp, Ep,
                  pts[(size_t)(b * 3 + 0) * N + n],
                  pts[(size_t)(b * 3 + 1) * N + n],
                  pts[(size_t)(b * 3 + 2) * N + n], idx, wgt);

    const unsigned short* base = ws + (size_t)bv * HW * Cc + q * 8;
    float acc[8];
    #pragma unroll
    for (int j = 0; j < 8; ++j) acc[j] = 0.0f;

    #pragma unroll
    for (int k = 0; k < 4; ++k) {
        const ux4 vv = *(const ux4*)(base + (size_t)idx[k] * Cc);
        const float w = wgt[k];
        #pragma unroll
        for (int j = 0; j < 4; ++j) {
            const unsigned int uu = vv[j];
            acc[2*j+0] = fmaf(__uint_as_float(uu << 16),         w, acc[2*j+0]);
            acc[2*j+1] = fmaf(__uint_as_float(uu & 0xffff0000u), w, acc[2*j+1]);
        }
    }

    float* obase = out + (size_t)bv * Cc * N + (size_t)(8 * q) * N + n;
    #pragma unroll
    for (int j = 0; j < 8; ++j)
        __builtin_nontemporal_store(acc[j], &obase[(size_t)j * N]);
}

// ---------------- fallback (R1 kernel) if ws too small ----------------
__global__ __launch_bounds__(BDIM) void feature_fetch_fallback(
    const float* __restrict__ fm, const float* __restrict__ pts,
    const float* __restrict__ Kmat, const float* __restrict__ Emat,
    float* __restrict__ out, int N)
{
    const int bv = blockIdx.y;
    const int b  = bv >> 2;
    const int n  = blockIdx.x * BDIM + threadIdx.x;
    if (n >= N) return;
    const float* Kp = Kmat + bv * 9;
    const float* Ep = Emat + bv * 12;
    int   idx[4];
    float wgt[4];
    project_point(Kp, Ep,
                  pts[(size_t)(b * 3 + 0) * N + n],
                  pts[(size_t)(b * 3 + 1) * N + n],
                  pts[(size_t)(b * 3 + 2) * N + n], idx, wgt);
    const float* basep = fm + (size_t)bv * Cc * HW;
    float* obase = out + (size_t)bv * Cc * N + n;
    #pragma unroll 4
    for (int c = 0; c < Cc; ++c) {
        const float* p = basep + (size_t)c * HW;
        obase[(size_t)c * N] = p[idx[0]] * wgt[0] + p[idx[1]] * wgt[1]
                             + p[idx[2]] * wgt[2] + p[idx[3]] * wgt[3];
    }
}

extern "C" void kernel_launch(void* const* d_in, const int* in_sizes, int n_in,
                              void* d_out, int out_size, void* d_ws, size_t ws_size,
                              hipStream_t stream) {
    const float* fm  = (const float*)d_in[0];
    const float* pts = (const float*)d_in[1];
    const float* K   = (const float*)d_in[2];
    const float* E   = (const float*)d_in[3];
    float* out = (float*)d_out;
    const int N = in_sizes[1] / 6;   // pts is [B=2, 3, N]

    const size_t need = (size_t)NBV * HW * Cc * sizeof(unsigned short); // 160 MB
    if (ws_size >= need) {
        unsigned short* ws = (unsigned short*)d_ws;
        dim3 tgrid(HW / 256, NBV);
        transpose_kernel<<<tgrid, 256, 0, stream>>>(fm, ws);
        if ((N & 1) == 0) {
            const int pts_per_block = (BDIM / 4) * 2;  // 128 points/block
            dim3 ggrid((N + pts_per_block - 1) / pts_per_block, NBV);
            gather2_kernel<<<ggrid, BDIM, 0, stream>>>(ws, pts, K, E, out, N);
        } else {
            const int pts_per_block = BDIM / 4;        // 64 points/block
            dim3 ggrid((N + pts_per_block - 1) / pts_per_block, NBV);
            gather_kernel<<<ggrid, BDIM, 0, stream>>>(ws, pts, K, E, out, N);
        }
    } else {
        dim3 grid((N + BDIM - 1) / BDIM, NBV);
        feature_fetch_fallback<<<grid, BDIM, 0, stream>>>(fm, pts, K, E, out, N);
    }
}